// Round 2
// baseline (150.695 us; speedup 1.0000x reference)
//
#include <hip/hip_runtime.h>

// 1D cubic B-spline field evaluation.
//   dx = 2/(num_cp-3); origin = -1-dx
//   tt = t - origin - dx  (== t + 1, computed stepwise to match reference rounding)
//   q = tt/dx; idx = floor(q); u = q - idx
//   out = sum_{k=0..3} w_k(u) * phi[clamp(idx+k, 0, num_cp-1)]
// Memory-bound: 128 MiB in + 128 MiB out; phi_x (32 KiB) is L1-resident.

__device__ __forceinline__ float bspline_eval(float tval, const float* __restrict__ phi,
                                              float origin, float dx, float inv_dx,
                                              int num_cp) {
    float tt = (tval - origin) - dx;   // matches reference op order
    float q  = tt * inv_dx;            // tt / dx
    float fidx = floorf(q);
    float u  = q - fidx;
    int idx = (int)fidx;

    int hi = num_cp - 1;
    int i0 = min(max(idx,     0), hi);
    int i1 = min(max(idx + 1, 0), hi);
    int i2 = min(max(idx + 2, 0), hi);
    int i3 = min(max(idx + 3, 0), hi);

    float v0 = phi[i0];
    float v1 = phi[i1];
    float v2 = phi[i2];
    float v3 = phi[i3];

    float u2 = u * u;
    float u3 = u2 * u;
    float om = 1.0f - u;
    const float sixth = 1.0f / 6.0f;
    float w0 = om * om * om * sixth;
    float w1 = (3.0f * u3 - 6.0f * u2 + 4.0f) * sixth;
    float w2 = (-3.0f * u3 + 3.0f * u2 + 3.0f * u + 1.0f) * sixth;
    float w3 = u3 * sixth;

    return w0 * v0 + w1 * v1 + w2 * v2 + w3 * v3;
}

__global__ __launch_bounds__(256) void bspline1d_kernel(
    const float* __restrict__ t,
    const float* __restrict__ phi,
    float* __restrict__ out,
    int num_cp, int n)
{
    const float dx     = 2.0f / (float)(num_cp - 3);
    const float origin = -1.0f - dx;
    const float inv_dx = (float)(num_cp - 3) * 0.5f;  // 1/dx

    const int tid    = blockIdx.x * blockDim.x + threadIdx.x;
    const int stride = gridDim.x * blockDim.x;
    const int n4     = n >> 2;

    const float4* __restrict__ t4 = reinterpret_cast<const float4*>(t);
    float4* __restrict__ o4       = reinterpret_cast<float4*>(out);

    for (int i = tid; i < n4; i += stride) {
        float4 tv = t4[i];
        float4 r;
        r.x = bspline_eval(tv.x, phi, origin, dx, inv_dx, num_cp);
        r.y = bspline_eval(tv.y, phi, origin, dx, inv_dx, num_cp);
        r.z = bspline_eval(tv.z, phi, origin, dx, inv_dx, num_cp);
        r.w = bspline_eval(tv.w, phi, origin, dx, inv_dx, num_cp);
        o4[i] = r;
    }

    // Tail (n not divisible by 4) — N_POINTS = 2^25 so normally empty.
    for (int i = (n4 << 2) + tid; i < n; i += stride) {
        out[i] = bspline_eval(t[i], phi, origin, dx, inv_dx, num_cp);
    }
}

extern "C" void kernel_launch(void* const* d_in, const int* in_sizes, int n_in,
                              void* d_out, int out_size, void* d_ws, size_t ws_size,
                              hipStream_t stream) {
    const float* t   = (const float*)d_in[0];
    const float* phi = (const float*)d_in[1];
    float* out       = (float*)d_out;
    const int n      = in_sizes[0];
    const int num_cp = in_sizes[1];

    const int block = 256;
    const int grid  = 2048;  // 256 CU * 8 blocks; grid-stride covers the rest
    bspline1d_kernel<<<grid, block, 0, stream>>>(t, phi, out, num_cp, n);
}

// Round 3
// 52.455 us; speedup vs baseline: 2.8729x; 2.8729x over previous
//
#include <hip/hip_runtime.h>

// 1D cubic B-spline field evaluation.
//   dx = 2/(num_cp-3); origin = -1-dx
//   tt = t - origin - dx; q = tt/dx; idx = floor(q); u = q - idx
//   out = sum_{k=0..3} w_k(u) * phi[clamp(idx+k, 0, num_cp-1)]
//
// R2 finding: bottleneck is divergent-gather serialization in L1 (~50 cyc per
// wave gather inst; 2^27/64 insts / 256 CU * 50cyc = 170us == measured 166us).
// Fix: stage phi (32 KiB) in LDS; random ds_read_b32 over 32 banks is ~2x the
// conflict-free 5.8cyc, ~5x faster than the L1 divergent path.

#define MAX_CP_LDS 8192

__device__ __forceinline__ float bspline_eval_lds(float tval, const float* sPhi,
                                                  float origin, float dx, float inv_dx,
                                                  int num_cp) {
    float tt = (tval - origin) - dx;   // matches reference op order
    float q  = tt * inv_dx;
    float fidx = floorf(q);
    float u  = q - fidx;
    int idx = (int)fidx;

    int hi = num_cp - 1;
    int i0 = min(max(idx,     0), hi);
    int i1 = min(max(idx + 1, 0), hi);
    int i2 = min(max(idx + 2, 0), hi);
    int i3 = min(max(idx + 3, 0), hi);

    float v0 = sPhi[i0];
    float v1 = sPhi[i1];
    float v2 = sPhi[i2];
    float v3 = sPhi[i3];

    float u2 = u * u;
    float u3 = u2 * u;
    float om = 1.0f - u;
    const float sixth = 1.0f / 6.0f;
    float w0 = om * om * om * sixth;
    float w1 = (3.0f * u3 - 6.0f * u2 + 4.0f) * sixth;
    float w2 = (-3.0f * u3 + 3.0f * u2 + 3.0f * u + 1.0f) * sixth;
    float w3 = u3 * sixth;

    return w0 * v0 + w1 * v1 + w2 * v2 + w3 * v3;
}

__global__ __launch_bounds__(256) void bspline1d_lds_kernel(
    const float* __restrict__ t,
    const float* __restrict__ phi,
    float* __restrict__ out,
    int num_cp, int n)
{
    __shared__ float sPhi[MAX_CP_LDS];

    // Stage phi into LDS with float4 loads: 8192 floats / 256 thr = 8 float4 each.
    {
        const float4* __restrict__ p4 = reinterpret_cast<const float4*>(phi);
        float4* s4 = reinterpret_cast<float4*>(sPhi);
        const int nc4 = num_cp >> 2;
        for (int j = threadIdx.x; j < nc4; j += blockDim.x) {
            s4[j] = p4[j];
        }
        for (int j = (nc4 << 2) + threadIdx.x; j < num_cp; j += blockDim.x) {
            sPhi[j] = phi[j];
        }
    }
    __syncthreads();

    const float dx     = 2.0f / (float)(num_cp - 3);
    const float origin = -1.0f - dx;
    const float inv_dx = (float)(num_cp - 3) * 0.5f;  // 1/dx

    const int tid    = blockIdx.x * blockDim.x + threadIdx.x;
    const int stride = gridDim.x * blockDim.x;
    const int n4     = n >> 2;

    const float4* __restrict__ t4 = reinterpret_cast<const float4*>(t);
    float4* __restrict__ o4       = reinterpret_cast<float4*>(out);

    for (int i = tid; i < n4; i += stride) {
        float4 tv = t4[i];
        float4 r;
        r.x = bspline_eval_lds(tv.x, sPhi, origin, dx, inv_dx, num_cp);
        r.y = bspline_eval_lds(tv.y, sPhi, origin, dx, inv_dx, num_cp);
        r.z = bspline_eval_lds(tv.z, sPhi, origin, dx, inv_dx, num_cp);
        r.w = bspline_eval_lds(tv.w, sPhi, origin, dx, inv_dx, num_cp);
        o4[i] = r;
    }

    for (int i = (n4 << 2) + tid; i < n; i += stride) {
        out[i] = bspline_eval_lds(t[i], sPhi, origin, dx, inv_dx, num_cp);
    }
}

// Fallback for num_cp > LDS capacity (not expected here): gather from global.
__global__ __launch_bounds__(256) void bspline1d_global_kernel(
    const float* __restrict__ t,
    const float* __restrict__ phi,
    float* __restrict__ out,
    int num_cp, int n)
{
    const float dx     = 2.0f / (float)(num_cp - 3);
    const float origin = -1.0f - dx;
    const float inv_dx = (float)(num_cp - 3) * 0.5f;

    const int tid    = blockIdx.x * blockDim.x + threadIdx.x;
    const int stride = gridDim.x * blockDim.x;
    for (int i = tid; i < n; i += stride) {
        out[i] = bspline_eval_lds(t[i], phi, origin, dx, inv_dx, num_cp);
    }
}

extern "C" void kernel_launch(void* const* d_in, const int* in_sizes, int n_in,
                              void* d_out, int out_size, void* d_ws, size_t ws_size,
                              hipStream_t stream) {
    const float* t   = (const float*)d_in[0];
    const float* phi = (const float*)d_in[1];
    float* out       = (float*)d_out;
    const int n      = in_sizes[0];
    const int num_cp = in_sizes[1];

    const int block = 256;
    const int grid  = 2048;

    if (num_cp <= MAX_CP_LDS) {
        bspline1d_lds_kernel<<<grid, block, 0, stream>>>(t, phi, out, num_cp, n);
    } else {
        bspline1d_global_kernel<<<grid, block, 0, stream>>>(t, phi, out, num_cp, n);
    }
}

// Round 5
// 47.871 us; speedup vs baseline: 3.1480x; 1.0958x over previous
//
#include <hip/hip_runtime.h>

// 1D cubic B-spline field evaluation.
//   dx = 2/(num_cp-3); origin = -1-dx
//   tt = t - origin - dx; q = tt/dx; idx = floor(q); u = q - idx
//   out = sum_{k=0..3} w_k(u) * phi[clamp(idx+k, 0, num_cp-1)]
//
// R2: L1 divergent-gather serialization was the wall (166us). R3: LDS staging
// -> 52us. R5: occupancy (block=512 -> 32 waves/CU), in-range fast path so the
// compiler can merge gathers into ds_read2_b32, w2 via partition-of-unity,
// nontemporal stores (via native vector type) to keep t resident in L3.

#define MAX_CP_LDS 8192
#define BLOCK 512

typedef float f4v __attribute__((ext_vector_type(4)));  // native vec for nontemporal builtin

__device__ __forceinline__ float bspline_eval_lds(float tval, const float* sPhi,
                                                  float origin, float dx, float inv_dx,
                                                  int num_cp) {
    float tt = (tval - origin) - dx;   // matches reference op order
    float q  = tt * inv_dx;
    float fidx = floorf(q);
    float u  = q - fidx;
    int idx = (int)fidx;
    int hi  = num_cp - 1;

    float v0, v1, v2, v3;
    if (__builtin_expect((unsigned)idx <= (unsigned)(hi - 3), 1)) {
        // In-range (always true for the bench data): consecutive reads,
        // compiler can merge into ds_read2_b32 pairs.
        v0 = sPhi[idx];
        v1 = sPhi[idx + 1];
        v2 = sPhi[idx + 2];
        v3 = sPhi[idx + 3];
    } else {
        int i0 = min(max(idx,     0), hi);
        int i1 = min(max(idx + 1, 0), hi);
        int i2 = min(max(idx + 2, 0), hi);
        int i3 = min(max(idx + 3, 0), hi);
        v0 = sPhi[i0]; v1 = sPhi[i1]; v2 = sPhi[i2]; v3 = sPhi[i3];
    }

    float u2 = u * u;
    float u3 = u2 * u;
    float om = 1.0f - u;
    const float sixth = 1.0f / 6.0f;
    float w0 = om * om * om * sixth;
    float w3 = u3 * sixth;
    float w1 = fmaf(0.5f, u3, fmaf(-1.0f, u2, 2.0f / 3.0f)); // (3u^3-6u^2+4)/6
    float w2 = 1.0f - w0 - w1 - w3;                          // partition of unity

    return fmaf(w0, v0, fmaf(w1, v1, fmaf(w2, v2, w3 * v3)));
}

__global__ __launch_bounds__(BLOCK) void bspline1d_lds_kernel(
    const float* __restrict__ t,
    const float* __restrict__ phi,
    float* __restrict__ out,
    int num_cp, int n)
{
    __shared__ float sPhi[MAX_CP_LDS];

    // Stage phi into LDS with float4 loads: 8192 floats / 512 thr = 4 float4 each.
    {
        const float4* __restrict__ p4 = reinterpret_cast<const float4*>(phi);
        float4* s4 = reinterpret_cast<float4*>(sPhi);
        const int nc4 = num_cp >> 2;
        for (int j = threadIdx.x; j < nc4; j += blockDim.x) {
            s4[j] = p4[j];
        }
        for (int j = (nc4 << 2) + threadIdx.x; j < num_cp; j += blockDim.x) {
            sPhi[j] = phi[j];
        }
    }
    __syncthreads();

    const float dx     = 2.0f / (float)(num_cp - 3);
    const float origin = -1.0f - dx;
    const float inv_dx = (float)(num_cp - 3) * 0.5f;  // 1/dx

    const int tid    = blockIdx.x * blockDim.x + threadIdx.x;
    const int stride = gridDim.x * blockDim.x;
    const int n4     = n >> 2;

    const float4* __restrict__ t4 = reinterpret_cast<const float4*>(t);
    f4v* __restrict__ o4          = reinterpret_cast<f4v*>(out);

    for (int i = tid; i < n4; i += stride) {
        float4 tv = t4[i];
        f4v r;
        r.x = bspline_eval_lds(tv.x, sPhi, origin, dx, inv_dx, num_cp);
        r.y = bspline_eval_lds(tv.y, sPhi, origin, dx, inv_dx, num_cp);
        r.z = bspline_eval_lds(tv.z, sPhi, origin, dx, inv_dx, num_cp);
        r.w = bspline_eval_lds(tv.w, sPhi, origin, dx, inv_dx, num_cp);
        __builtin_nontemporal_store(r, &o4[i]);  // out never re-read: keep t in L3
    }

    for (int i = (n4 << 2) + tid; i < n; i += stride) {
        float v = bspline_eval_lds(t[i], sPhi, origin, dx, inv_dx, num_cp);
        __builtin_nontemporal_store(v, &out[i]);
    }
}

// Fallback for num_cp > LDS capacity (not expected here): gather from global.
__global__ __launch_bounds__(BLOCK) void bspline1d_global_kernel(
    const float* __restrict__ t,
    const float* __restrict__ phi,
    float* __restrict__ out,
    int num_cp, int n)
{
    const float dx     = 2.0f / (float)(num_cp - 3);
    const float origin = -1.0f - dx;
    const float inv_dx = (float)(num_cp - 3) * 0.5f;

    const int tid    = blockIdx.x * blockDim.x + threadIdx.x;
    const int stride = gridDim.x * blockDim.x;
    for (int i = tid; i < n; i += stride) {
        out[i] = bspline_eval_lds(t[i], phi, origin, dx, inv_dx, num_cp);
    }
}

extern "C" void kernel_launch(void* const* d_in, const int* in_sizes, int n_in,
                              void* d_out, int out_size, void* d_ws, size_t ws_size,
                              hipStream_t stream) {
    const float* t   = (const float*)d_in[0];
    const float* phi = (const float*)d_in[1];
    float* out       = (float*)d_out;
    const int n      = in_sizes[0];
    const int num_cp = in_sizes[1];

    const int grid = 2048;  // 1M threads, 8 float4 iters each; 4 blocks/CU resident

    if (num_cp <= MAX_CP_LDS) {
        bspline1d_lds_kernel<<<grid, BLOCK, 0, stream>>>(t, phi, out, num_cp, n);
    } else {
        bspline1d_global_kernel<<<grid, BLOCK, 0, stream>>>(t, phi, out, num_cp, n);
    }
}